// Round 1
// baseline (58.948 us; speedup 1.0000x reference)
//
#include <hip/hip_runtime.h>

// Problem constants
#define B_ 4
#define T_ 1024
#define D_ 1024
#define H_ 2048
#define E_ 8
#define N_ (B_ * T_)

// --------------------------------------------------------------------------
// Kernel 1: w2sum[e*H + j] = sum_d w2[e, j, d]   (w2 layout [E, H, D])
// One wave per row of D=1024 contiguous floats. 16384 waves.
// --------------------------------------------------------------------------
__global__ void w2_rowsum_kernel(const float* __restrict__ w2,
                                 float* __restrict__ w2sum) {
    int wave = (blockIdx.x * blockDim.x + threadIdx.x) >> 6;
    int lane = threadIdx.x & 63;
    const float4* row4 = (const float4*)(w2 + (size_t)wave * D_);
    float acc = 0.f;
#pragma unroll
    for (int k = 0; k < D_ / 256; ++k) {          // 4 iters
        float4 a = row4[lane + 64 * k];
        acc += a.x + a.y + a.z + a.w;
    }
#pragma unroll
    for (int off = 32; off >= 1; off >>= 1) acc += __shfl_xor(acc, off, 64);
    if (lane == 0) w2sum[wave] = acc;
}

// --------------------------------------------------------------------------
// Kernel 2: v[e*D + d] = dot(w1[e, d, :], w2sum[e, :])   (w1 layout [E, D, H])
// One wave per (e,d). 8192 waves.
// --------------------------------------------------------------------------
__global__ void v_build_kernel(const float* __restrict__ w1,
                               const float* __restrict__ w2sum,
                               float* __restrict__ v) {
    int wave = (blockIdx.x * blockDim.x + threadIdx.x) >> 6;
    int lane = threadIdx.x & 63;
    int e = wave >> 10;                            // wave / D_
    const float4* row4 = (const float4*)(w1 + (size_t)wave * H_);
    const float4* ws4  = (const float4*)(w2sum + e * H_);
    float acc = 0.f;
#pragma unroll
    for (int k = 0; k < H_ / 256; ++k) {          // 8 iters
        float4 a = row4[lane + 64 * k];
        float4 b = ws4[lane + 64 * k];
        acc += a.x * b.x + a.y * b.y + a.z * b.z + a.w * b.w;
    }
#pragma unroll
    for (int off = 32; off >= 1; off >>= 1) acc += __shfl_xor(acc, off, 64);
    if (lane == 0) v[wave] = acc;
}

// --------------------------------------------------------------------------
// Kernel 3: c[e] = dot(b1[e,:], w2sum[e,:]) + sum_d b2[e,d]
// One wave per expert, single block of 512 threads.
// --------------------------------------------------------------------------
__global__ void c_build_kernel(const float* __restrict__ b1,
                               const float* __restrict__ w2sum,
                               const float* __restrict__ b2,
                               float* __restrict__ c) {
    int e = threadIdx.x >> 6;
    int lane = threadIdx.x & 63;
    float acc = 0.f;
    for (int k = lane; k < H_; k += 64) acc += b1[e * H_ + k] * w2sum[e * H_ + k];
    for (int k = lane; k < D_; k += 64) acc += b2[e * D_ + k];
#pragma unroll
    for (int off = 32; off >= 1; off >>= 1) acc += __shfl_xor(acc, off, 64);
    if (lane == 0) c[e] = acc;
}

// --------------------------------------------------------------------------
// Kernel 4: per-token gating + collapsed expert sum.
//   logits[e] = x[n,:] . wg[:,e]       (wg layout [D, E])
//   dv[e]     = x[n,:] . v[e,:]
//   top-2 of logits (tie -> lower index), g1 = 1/(1+exp(l0-l1))
//   s[n] = g0*(dv[e0]+c[e0]) + g1*(dv[e1]+c[e1])
// One wave per token. 4096 waves.
// --------------------------------------------------------------------------
__global__ void token_kernel(const float* __restrict__ x,
                             const float* __restrict__ wg,
                             const float* __restrict__ v,
                             const float* __restrict__ c,
                             float* __restrict__ s) {
    int n = (blockIdx.x * blockDim.x + threadIdx.x) >> 6;
    int lane = threadIdx.x & 63;
    const float* xr = x + (size_t)n * D_;

    float lg[E_] = {0.f, 0.f, 0.f, 0.f, 0.f, 0.f, 0.f, 0.f};
    float dv[E_] = {0.f, 0.f, 0.f, 0.f, 0.f, 0.f, 0.f, 0.f};

#pragma unroll
    for (int k = 0; k < D_ / 64; ++k) {           // 16 iters, stride-64 coalesced
        int d = lane + 64 * k;
        float xv = xr[d];
        const float4* wgp = (const float4*)(wg + (size_t)d * E_);  // 8 consecutive
        float4 g0 = wgp[0], g1 = wgp[1];
        lg[0] += xv * g0.x; lg[1] += xv * g0.y;
        lg[2] += xv * g0.z; lg[3] += xv * g0.w;
        lg[4] += xv * g1.x; lg[5] += xv * g1.y;
        lg[6] += xv * g1.z; lg[7] += xv * g1.w;
#pragma unroll
        for (int e = 0; e < E_; ++e) dv[e] += xv * v[e * D_ + d];
    }

#pragma unroll
    for (int off = 32; off >= 1; off >>= 1) {
#pragma unroll
        for (int e = 0; e < E_; ++e) {
            lg[e] += __shfl_xor(lg[e], off, 64);
            dv[e] += __shfl_xor(dv[e], off, 64);
        }
    }

    if (lane == 0) {
        // top-2 with jax.lax.top_k tie-breaking (lower index first)
        int e0 = 0;
#pragma unroll
        for (int e = 1; e < E_; ++e) if (lg[e] > lg[e0]) e0 = e;
        int e1 = (e0 == 0) ? 1 : 0;
#pragma unroll
        for (int e = 0; e < E_; ++e) {
            if (e == e0) continue;
            if (lg[e] > lg[e1]) e1 = e;
        }
        float l0 = lg[e0], l1 = lg[e1];
        float g1w = 1.f / (1.f + expf(l0 - l1));   // exp(l1)/(exp(l0)+exp(l1))
        float g0w = 1.f - g1w;
        s[n] = g0w * (dv[e0] + c[e0]) + g1w * (dv[e1] + c[e1]);
    }
}

// --------------------------------------------------------------------------
// Kernel 5: out[b, t] = s[b, t] - logsumexp_t(s[b, :])   (T = 1024)
// One block of 256 threads per batch row.
// --------------------------------------------------------------------------
__global__ void lsm_kernel(const float* __restrict__ s, float* __restrict__ out) {
    int b = blockIdx.x;
    int t = threadIdx.x;
    const float* row = s + (size_t)b * T_;
    __shared__ float red[256];

    float vals[4];
    float mx = -3.0e38f;
#pragma unroll
    for (int k = 0; k < 4; ++k) {
        vals[k] = row[t + 256 * k];
        mx = fmaxf(mx, vals[k]);
    }
    red[t] = mx;
    __syncthreads();
    for (int off = 128; off >= 1; off >>= 1) {
        if (t < off) red[t] = fmaxf(red[t], red[t + off]);
        __syncthreads();
    }
    mx = red[0];
    __syncthreads();

    float sm = 0.f;
#pragma unroll
    for (int k = 0; k < 4; ++k) sm += expf(vals[k] - mx);
    red[t] = sm;
    __syncthreads();
    for (int off = 128; off >= 1; off >>= 1) {
        if (t < off) red[t] += red[t + off];
        __syncthreads();
    }
    float lse = mx + logf(red[0]);

#pragma unroll
    for (int k = 0; k < 4; ++k) out[(size_t)b * T_ + t + 256 * k] = vals[k] - lse;
}

// --------------------------------------------------------------------------
extern "C" void kernel_launch(void* const* d_in, const int* in_sizes, int n_in,
                              void* d_out, int out_size, void* d_ws, size_t ws_size,
                              hipStream_t stream) {
    const float* x  = (const float*)d_in[0];   // [B, T, D]
    const float* wg = (const float*)d_in[1];   // [D, E]
    const float* w1 = (const float*)d_in[2];   // [E, D, H]
    const float* b1 = (const float*)d_in[3];   // [E, H]
    const float* w2 = (const float*)d_in[4];   // [E, H, D]
    const float* b2 = (const float*)d_in[5];   // [E, D]
    float* out = (float*)d_out;                // [B, T]

    float* ws     = (float*)d_ws;
    float* w2sum  = ws;                // E*H   = 16384 floats
    float* v      = ws + 16384;        // E*D   =  8192 floats
    float* c      = ws + 24576;        // E     =     8 floats
    float* s      = ws + 24592;        // N     =  4096 floats

    // 1) w2 row sums: E*H = 16384 waves, 4 waves/block -> 4096 blocks
    w2_rowsum_kernel<<<dim3(4096), dim3(256), 0, stream>>>(w2, w2sum);
    // 2) v = w1 . w2sum : E*D = 8192 waves -> 2048 blocks
    v_build_kernel<<<dim3(2048), dim3(256), 0, stream>>>(w1, w2sum, v);
    // 3) c[e]
    c_build_kernel<<<dim3(1), dim3(512), 0, stream>>>(b1, w2sum, b2, c);
    // 4) per-token gating + collapsed expert sum: 4096 waves -> 1024 blocks
    token_kernel<<<dim3(1024), dim3(256), 0, stream>>>(x, wg, v, c, s);
    // 5) log-softmax over T per batch row
    lsm_kernel<<<dim3(B_), dim3(256), 0, stream>>>(s, out);
}